// Round 7
// baseline (256.842 us; speedup 1.0000x reference)
//
#include <hip/hip_runtime.h>

// MaxUnPooling2DArgMax via block-sorted direct-slab binning (2 kernels).
// B=8, in/batch=2^20, out/batch=2^22, N=2^23 pairs, out total 2^25 floats.
// Bin = 8192 floats (32 KB of output). 512 bins/batch, 4096 bins total.
//
// R7: (1) kA uses 1024-thread blocks (70 KB LDS, 2 blocks/CU -> 32 waves/CU
// full occupancy, was 16). (2) Per-(block,bin) slab reservations rounded up
// to 8 pairs = 64 B so every slab cache line is fully written (no L2
// write-allocate RMW of poisoned lines); pad slots hold sentinel (0,0) which
// kB accumulates as acc[0] += 0.0f (harmless). Counts stay multiples of 8 so
// kB's uint4 loop has no tail. (3) NT loads for streamed inputs, NT store
// for output. CAP=3072 (mean 2048+~512 pad; drop-guard on overflow).
// Fixed harness overhead measured ~132 us (ws/out poison + in restore).

typedef unsigned int u32;
typedef float nat_f4 __attribute__((ext_vector_type(4)));
typedef u32   nat_u4 __attribute__((ext_vector_type(4)));

constexpr int N             = 1 << 23;  // input pairs
constexpr int NBINS         = 4096;
constexpr int BINS_PER_B    = 512;      // per batch
constexpr int BIN_FLOATS    = 8192;     // 32 KB
constexpr int CAP           = 3072;     // slab slots per bin (mult of 8)
constexpr int KA_BLOCKS     = 1024;
constexpr int PAIRS_PER_BLK = 8192;     // N / KA_BLOCKS
constexpr size_t SLAB_BYTES = (size_t)NBINS * CAP * 8;
constexpr size_t WS_NEEDED  = SLAB_BYTES + (size_t)NBINS * 4;

// ---------------- kA: LDS counting sort -> aligned per-bin slab flush ----------------
__global__ __launch_bounds__(1024, 8) void kA_sort(const nat_u4* __restrict__ idx4,
                                                   const nat_f4* __restrict__ val4,
                                                   uint2* __restrict__ slab,
                                                   u32* __restrict__ cursor) {
    __shared__ u32 lhist[BINS_PER_B];    // per-bin counts (then reread for pads)
    __shared__ u32 lstart[BINS_PER_B];   // local exclusive scan
    __shared__ u32 lbase[BINS_PER_B];    // global slab offset from cursor
    __shared__ u32 wsum[8];
    __shared__ uint2 sorted[PAIRS_PER_BLK];  // 64 KB, bin-sorted (val_bits, idx22)

    const int tid = threadIdx.x;
    if (tid < BINS_PER_B) lhist[tid] = 0;
    __syncthreads();

    const int cb4 = blockIdx.x * (PAIRS_PER_BLK / 4);   // 2048 vec4 per block
    const u32 bb  = (u32)(blockIdx.x >> 7) << 9;        // batch * 512

    nat_u4 ix[2];
    nat_f4 vv[2];
    u32    rr[8];   // per-pair rank within its bin (from hist atomicAdd)
#pragma unroll
    for (int i = 0; i < 2; ++i) {
        ix[i] = __builtin_nontemporal_load(&idx4[cb4 + i * 1024 + tid]);
        vv[i] = __builtin_nontemporal_load(&val4[cb4 + i * 1024 + tid]);
    }
#pragma unroll
    for (int i = 0; i < 2; ++i)
#pragma unroll
        for (int c = 0; c < 4; ++c)
            rr[4 * i + c] = atomicAdd(&lhist[ix[i][c] >> 13], 1u);
    __syncthreads();

    // Exclusive scan of 512 bin counts: waves 0..7 (tid<512), one bin/thread.
    if (tid < BINS_PER_B) {
        const int lane = tid & 63, w = tid >> 6;
        const u32 v = lhist[tid];
        u32 s = v;
#pragma unroll
        for (int d = 1; d < 64; d <<= 1) {
            u32 t = __shfl_up(s, d);
            if (lane >= d) s += t;
        }
        if (lane == 63) wsum[w] = s;
        __syncthreads();
        if (tid == 0) {
            u32 acc = 0;
#pragma unroll
            for (int i = 0; i < 8; ++i) { u32 t = wsum[i]; wsum[i] = acc; acc += t; }
        }
        __syncthreads();
        lstart[tid] = s - v + wsum[w];
        // Reserve a 64 B-aligned range (round count to multiple of 8).
        const u32 r8 = (v + 7u) & ~7u;
        lbase[tid] = r8 ? atomicAdd(&cursor[bb + tid], r8) : 0u;
    } else {
        __syncthreads();
        __syncthreads();
    }
    __syncthreads();

    // Placement via precomputed ranks: plain LDS writes, no atomics.
#pragma unroll
    for (int i = 0; i < 2; ++i)
#pragma unroll
        for (int c = 0; c < 4; ++c)
            sorted[lstart[ix[i][c] >> 13] + rr[4 * i + c]] =
                make_uint2(__float_as_uint(vv[i][c]), ix[i][c]);
    __syncthreads();

    // Flush real pairs: runs start 64 B-aligned -> full-line writes.
#pragma unroll
    for (int k = 0; k < 8; ++k) {
        int j = k * 1024 + tid;
        uint2 p = sorted[j];
        u32 b = p.y >> 13;
        u32 r = lbase[b] + ((u32)j - lstart[b]);   // global rank within bin
        if (r < (u32)CAP)                          // overflow drop-guard
            slab[(size_t)(bb + b) * CAP + r] = make_uint2(p.x, p.y & 8191u);
    }
    // Sentinel-pad each run's tail to its 64 B boundary: (0,0) -> acc[0]+=0.f.
    if (tid < BINS_PER_B) {
        const u32 v = lhist[tid];
        const u32 r8 = (v + 7u) & ~7u;
        uint2* sb = slab + (size_t)(bb + tid) * CAP;
        for (u32 q = v; q < r8; ++q) {
            u32 r = lbase[tid] + q;
            if (r < (u32)CAP) sb[r] = make_uint2(0u, 0u);
        }
    }
}

// ---------------- kB: contiguous slab read + LDS accumulate + NT stream ----------------
__global__ __launch_bounds__(512) void kB_accum(const uint2* __restrict__ slab,
                                                const u32* __restrict__ cursor,
                                                float* __restrict__ out) {
    __shared__ float acc[BIN_FLOATS];   // 32 KB
    const int bin = blockIdx.x, tid = threadIdx.x;

    nat_f4* a4 = (nat_f4*)acc;
#pragma unroll
    for (int i = 0; i < 4; ++i) a4[tid + i * 512] = (nat_f4)0.f;
    u32 cnt = cursor[bin];
    if (cnt > (u32)CAP) cnt = (u32)CAP;   // always a multiple of 8
    const uint4* seg4 = (const uint4*)(slab + (size_t)bin * CAP);
    __syncthreads();

    // Contiguous gather: 2 pairs per uint4 load; no tail (cnt % 8 == 0).
    const u32 half = cnt >> 1;
    for (u32 j = tid; j < half; j += 512) {
        uint4 p = seg4[j];
        atomicAdd(&acc[p.y], __uint_as_float(p.x));
        atomicAdd(&acc[p.w], __uint_as_float(p.z));
    }
    __syncthreads();

    // Stream bin out (nontemporal: written once, never re-read).
    nat_f4* o4 = (nat_f4*)(out + ((size_t)bin << 13));
#pragma unroll
    for (int i = 0; i < 4; ++i)
        __builtin_nontemporal_store(a4[tid + i * 512], &o4[tid + i * 512]);
}

// ---------------- Fallback (ws too small): zero + device-atomic scatter ----------------
__global__ __launch_bounds__(256) void zero_out(float4* __restrict__ out) {
    int t = blockIdx.x * blockDim.x + threadIdx.x;
    out[t] = make_float4(0.f, 0.f, 0.f, 0.f);
}
__global__ __launch_bounds__(256) void scatter_atomic(const float4* __restrict__ in,
                                                      const int4* __restrict__ idx,
                                                      float* __restrict__ out) {
    int t = blockIdx.x * blockDim.x + threadIdx.x;
    float4 v = in[t];
    int4 ix = idx[t];
    float* obase = out + ((size_t)(t >> 18) << 22);
    atomicAdd(obase + ix.x, v.x);
    atomicAdd(obase + ix.y, v.y);
    atomicAdd(obase + ix.z, v.z);
    atomicAdd(obase + ix.w, v.w);
}

extern "C" void kernel_launch(void* const* d_in, const int* in_sizes, int n_in,
                              void* d_out, int out_size, void* d_ws, size_t ws_size,
                              hipStream_t stream) {
    const float4* val4 = (const float4*)d_in[0];
    const int4*   idx4 = (const int4*)d_in[1];
    float*        out  = (float*)d_out;

    if (ws_size < WS_NEEDED) {
        // Fallback: fast zero + device atomics (R1 structure).
        zero_out<<<(out_size / 4) / 256, 256, 0, stream>>>((float4*)d_out);
        scatter_atomic<<<(N / 4) / 256, 256, 0, stream>>>(val4, idx4, out);
        return;
    }

    uint2* slab   = (uint2*)d_ws;
    u32*   cursor = (u32*)((char*)d_ws + SLAB_BYTES);

    (void)hipMemsetAsync(cursor, 0, NBINS * sizeof(u32), stream);
    kA_sort <<<KA_BLOCKS, 1024, 0, stream>>>((const nat_u4*)idx4, (const nat_f4*)val4,
                                             slab, cursor);
    kB_accum<<<NBINS, 512, 0, stream>>>(slab, cursor, out);
}

// Round 8
// 246.655 us; speedup vs baseline: 1.0413x; 1.0413x over previous
//
#include <hip/hip_runtime.h>

// MaxUnPooling2DArgMax via block-sorted direct-slab binning (2 kernels).
// B=8, in/batch=2^20, out/batch=2^22, N=2^23 pairs, out total 2^25 floats.
// R8: bin = 16384 floats (64 KB out). 256 bins/batch, 2048 bins total.
// bin = (batch<<8)|(idx>>14), off = idx & 16383.
//
// Mean run per (kA block, bin) = 32 pairs = 256 B -> scattered slab writes
// are mostly full 128 B lines. Exact reservations (no pad pass, R7's pad
// loop regressed). NT loads/stores throughout: inputs, slab flush, slab
// read, output stream. kA: 1024 thr, 70 KB LDS, 2 blk/CU (full occupancy).
// kB: 1024 thr, 64 KB LDS, 2 blk/CU. CAP=5120 (mean 4096, sigma~64 -> 16s).
// Fixed harness overhead ~136 us (ws/out poison + in restore) is untouchable.

typedef unsigned int u32;
typedef float nat_f4 __attribute__((ext_vector_type(4)));
typedef u32   nat_u4 __attribute__((ext_vector_type(4)));
typedef u32   nat_u2 __attribute__((ext_vector_type(2)));

constexpr int N             = 1 << 23;  // input pairs
constexpr int BINS_PER_B    = 256;      // per batch
constexpr int NBINS         = 2048;     // total
constexpr int BIN_FLOATS    = 16384;    // 64 KB of output per bin
constexpr int BIN_SHIFT     = 14;
constexpr u32 BIN_MASK      = 16383u;
constexpr int CAP           = 5120;     // slab slots per bin
constexpr int KA_BLOCKS     = 1024;
constexpr int PAIRS_PER_BLK = 8192;     // N / KA_BLOCKS
constexpr size_t SLAB_BYTES = (size_t)NBINS * CAP * 8;
constexpr size_t WS_NEEDED  = SLAB_BYTES + (size_t)NBINS * 4;

// ---------------- kA: LDS counting sort -> per-bin slab flush (NT) ----------------
__global__ __launch_bounds__(1024, 8) void kA_sort(const nat_u4* __restrict__ idx4,
                                                   const nat_f4* __restrict__ val4,
                                                   nat_u2* __restrict__ slab,
                                                   u32* __restrict__ cursor) {
    __shared__ u32 lhist[BINS_PER_B];    // per-bin counts
    __shared__ u32 lstart[BINS_PER_B];   // local exclusive scan
    __shared__ u32 lbase[BINS_PER_B];    // global slab offset from cursor
    __shared__ u32 wsum[4];
    __shared__ uint2 sorted[PAIRS_PER_BLK];  // 64 KB, bin-sorted (val_bits, idx22)

    const int tid = threadIdx.x;
    if (tid < BINS_PER_B) lhist[tid] = 0;
    __syncthreads();

    const int cb4 = blockIdx.x * (PAIRS_PER_BLK / 4);   // 2048 vec4 per block
    const u32 bb  = (u32)(blockIdx.x >> 7) << 8;        // batch * 256

    nat_u4 ix[2];
    nat_f4 vv[2];
    u32    rr[8];   // per-pair rank within its bin (from hist atomicAdd)
#pragma unroll
    for (int i = 0; i < 2; ++i) {
        ix[i] = __builtin_nontemporal_load(&idx4[cb4 + i * 1024 + tid]);
        vv[i] = __builtin_nontemporal_load(&val4[cb4 + i * 1024 + tid]);
    }
#pragma unroll
    for (int i = 0; i < 2; ++i)
#pragma unroll
        for (int c = 0; c < 4; ++c)
            rr[4 * i + c] = atomicAdd(&lhist[ix[i][c] >> BIN_SHIFT], 1u);
    __syncthreads();

    // Exclusive scan of 256 bin counts (waves 0..3, one bin per thread).
    if (tid < BINS_PER_B) {
        const int lane = tid & 63, w = tid >> 6;
        const u32 v = lhist[tid];
        u32 s = v;
#pragma unroll
        for (int d = 1; d < 64; d <<= 1) {
            u32 t = __shfl_up(s, d);
            if (lane >= d) s += t;
        }
        if (lane == 63) wsum[w] = s;
        __syncthreads();
        if (tid == 0) {
            u32 acc = 0;
#pragma unroll
            for (int i = 0; i < 4; ++i) { u32 t = wsum[i]; wsum[i] = acc; acc += t; }
        }
        __syncthreads();
        lstart[tid] = s - v + wsum[w];
        lbase[tid]  = v ? atomicAdd(&cursor[bb + tid], v) : 0u;  // exact reserve
    } else {
        __syncthreads();
        __syncthreads();
    }
    __syncthreads();

    // Placement via precomputed ranks: plain LDS writes, no atomics.
#pragma unroll
    for (int i = 0; i < 2; ++i)
#pragma unroll
        for (int c = 0; c < 4; ++c)
            sorted[lstart[ix[i][c] >> BIN_SHIFT] + rr[4 * i + c]] =
                make_uint2(__float_as_uint(vv[i][c]), ix[i][c]);
    __syncthreads();

    // Flush: ~32-pair (256 B) runs -> mostly full-line NT stores.
#pragma unroll
    for (int k = 0; k < 8; ++k) {
        int j = k * 1024 + tid;
        uint2 p = sorted[j];
        u32 b = p.y >> BIN_SHIFT;
        u32 r = lbase[b] + ((u32)j - lstart[b]);   // global rank within bin
        if (r < (u32)CAP) {                        // overflow drop-guard
            nat_u2 q = {p.x, p.y & BIN_MASK};
            __builtin_nontemporal_store(q, &slab[(size_t)(bb + b) * CAP + r]);
        }
    }
}

// ---------------- kB: contiguous slab read + LDS accumulate + NT stream ----------------
__global__ __launch_bounds__(1024, 2) void kB_accum(const nat_u4* __restrict__ slab4,
                                                    const u32* __restrict__ cursor,
                                                    float* __restrict__ out) {
    __shared__ float acc[BIN_FLOATS];   // 64 KB
    const int bin = blockIdx.x, tid = threadIdx.x;

    nat_f4* a4 = (nat_f4*)acc;
#pragma unroll
    for (int i = 0; i < 4; ++i) a4[tid + i * 1024] = (nat_f4)0.f;
    u32 cnt = cursor[bin];
    if (cnt > (u32)CAP) cnt = (u32)CAP;
    const nat_u4* seg4 = slab4 + (size_t)bin * (CAP / 2);
    __syncthreads();

    // Contiguous gather: 2 pairs per 16 B NT load.
    const u32 half = cnt >> 1;
    for (u32 j = tid; j < half; j += 1024) {
        nat_u4 p = __builtin_nontemporal_load(&seg4[j]);
        atomicAdd(&acc[p.y], __uint_as_float(p.x));
        atomicAdd(&acc[p.w], __uint_as_float(p.z));
    }
    if (tid == 0 && (cnt & 1u)) {
        const nat_u2* seg2 = (const nat_u2*)seg4;
        nat_u2 p = __builtin_nontemporal_load(&seg2[cnt - 1]);
        atomicAdd(&acc[p.y], __uint_as_float(p.x));
    }
    __syncthreads();

    // Stream bin out (nontemporal: written once, never re-read).
    nat_f4* o4 = (nat_f4*)(out + ((size_t)bin << BIN_SHIFT));
#pragma unroll
    for (int i = 0; i < 4; ++i)
        __builtin_nontemporal_store(a4[tid + i * 1024], &o4[tid + i * 1024]);
}

// ---------------- Fallback (ws too small): zero + device-atomic scatter ----------------
__global__ __launch_bounds__(256) void zero_out(float4* __restrict__ out) {
    int t = blockIdx.x * blockDim.x + threadIdx.x;
    out[t] = make_float4(0.f, 0.f, 0.f, 0.f);
}
__global__ __launch_bounds__(256) void scatter_atomic(const float4* __restrict__ in,
                                                      const int4* __restrict__ idx,
                                                      float* __restrict__ out) {
    int t = blockIdx.x * blockDim.x + threadIdx.x;
    float4 v = in[t];
    int4 ix = idx[t];
    float* obase = out + ((size_t)(t >> 18) << 22);
    atomicAdd(obase + ix.x, v.x);
    atomicAdd(obase + ix.y, v.y);
    atomicAdd(obase + ix.z, v.z);
    atomicAdd(obase + ix.w, v.w);
}

extern "C" void kernel_launch(void* const* d_in, const int* in_sizes, int n_in,
                              void* d_out, int out_size, void* d_ws, size_t ws_size,
                              hipStream_t stream) {
    const float4* val4 = (const float4*)d_in[0];
    const int4*   idx4 = (const int4*)d_in[1];
    float*        out  = (float*)d_out;

    if (ws_size < WS_NEEDED) {
        // Fallback: fast zero + device atomics (R1 structure).
        zero_out<<<(out_size / 4) / 256, 256, 0, stream>>>((float4*)d_out);
        scatter_atomic<<<(N / 4) / 256, 256, 0, stream>>>(val4, idx4, out);
        return;
    }

    nat_u2* slab   = (nat_u2*)d_ws;
    u32*    cursor = (u32*)((char*)d_ws + SLAB_BYTES);

    (void)hipMemsetAsync(cursor, 0, NBINS * sizeof(u32), stream);
    kA_sort <<<KA_BLOCKS, 1024, 0, stream>>>((const nat_u4*)idx4, (const nat_f4*)val4,
                                             slab, cursor);
    kB_accum<<<NBINS, 1024, 0, stream>>>((const nat_u4*)d_ws, cursor, out);
}

// Round 9
// 237.868 us; speedup vs baseline: 1.0798x; 1.0369x over previous
//
#include <hip/hip_runtime.h>

// MaxUnPooling2DArgMax via block-sorted direct-slab binning (2 kernels).
// B=8, in/batch=2^20, out/batch=2^22, N=2^23 pairs, out total 2^25 floats.
// Bin = 16384 floats (64 KB out). 256 bins/batch, 2048 bins total.
// bin = (batch<<8)|(idx>>14), off = idx & 16383.
//
// R9 deltas vs R8:
//  - Slab stores/loads are CACHED again (NT only on input loads + output
//    stream). Slab = 80 MB written once, read once -> let L2/L3 carry it
//    instead of forcing an HBM round-trip with NT hints.
//  - kA flush uses one fused diff[] = lbase-lstart LDS array (1 LDS read
//    per pair instead of 2).
//  - kB gather: 2 independent uint4 loads per iteration (4 pairs, 2x MLP).
// Fixed harness overhead ~121 us (ws/out poison + in restore) is untouchable.

typedef unsigned int u32;
typedef float nat_f4 __attribute__((ext_vector_type(4)));
typedef u32   nat_u4 __attribute__((ext_vector_type(4)));

constexpr int N             = 1 << 23;  // input pairs
constexpr int BINS_PER_B    = 256;      // per batch
constexpr int NBINS         = 2048;     // total
constexpr int BIN_FLOATS    = 16384;    // 64 KB of output per bin
constexpr int BIN_SHIFT     = 14;
constexpr u32 BIN_MASK      = 16383u;
constexpr int CAP           = 5120;     // slab slots per bin
constexpr int KA_BLOCKS     = 1024;
constexpr int PAIRS_PER_BLK = 8192;     // N / KA_BLOCKS
constexpr size_t SLAB_BYTES = (size_t)NBINS * CAP * 8;
constexpr size_t WS_NEEDED  = SLAB_BYTES + (size_t)NBINS * 4;

// ---------------- kA: LDS counting sort -> per-bin slab flush ----------------
__global__ __launch_bounds__(1024, 8) void kA_sort(const nat_u4* __restrict__ idx4,
                                                   const nat_f4* __restrict__ val4,
                                                   uint2* __restrict__ slab,
                                                   u32* __restrict__ cursor) {
    __shared__ u32 lhist[BINS_PER_B];    // per-bin counts
    __shared__ u32 lstart[BINS_PER_B];   // local exclusive scan
    __shared__ u32 diff[BINS_PER_B];     // lbase - lstart (fused flush table)
    __shared__ u32 wsum[4];
    __shared__ uint2 sorted[PAIRS_PER_BLK];  // 64 KB, bin-sorted (val_bits, idx22)

    const int tid = threadIdx.x;
    if (tid < BINS_PER_B) lhist[tid] = 0;
    __syncthreads();

    const int cb4 = blockIdx.x * (PAIRS_PER_BLK / 4);   // 2048 vec4 per block
    const u32 bb  = (u32)(blockIdx.x >> 7) << 8;        // batch * 256

    nat_u4 ix[2];
    nat_f4 vv[2];
    u32    rr[8];   // per-pair rank within its bin (from hist atomicAdd)
#pragma unroll
    for (int i = 0; i < 2; ++i) {
        ix[i] = __builtin_nontemporal_load(&idx4[cb4 + i * 1024 + tid]);
        vv[i] = __builtin_nontemporal_load(&val4[cb4 + i * 1024 + tid]);
    }
#pragma unroll
    for (int i = 0; i < 2; ++i)
#pragma unroll
        for (int c = 0; c < 4; ++c)
            rr[4 * i + c] = atomicAdd(&lhist[ix[i][c] >> BIN_SHIFT], 1u);
    __syncthreads();

    // Exclusive scan of 256 bin counts (waves 0..3, one bin per thread).
    if (tid < BINS_PER_B) {
        const int lane = tid & 63, w = tid >> 6;
        const u32 v = lhist[tid];
        u32 s = v;
#pragma unroll
        for (int d = 1; d < 64; d <<= 1) {
            u32 t = __shfl_up(s, d);
            if (lane >= d) s += t;
        }
        if (lane == 63) wsum[w] = s;
        __syncthreads();
        if (tid == 0) {
            u32 acc = 0;
#pragma unroll
            for (int i = 0; i < 4; ++i) { u32 t = wsum[i]; wsum[i] = acc; acc += t; }
        }
        __syncthreads();
        const u32 ls = s - v + wsum[w];
        lstart[tid] = ls;
        const u32 lb = v ? atomicAdd(&cursor[bb + tid], v) : 0u;  // exact reserve
        diff[tid] = lb - ls;   // r = j + diff[b] (mod 2^32 arithmetic is fine)
    } else {
        __syncthreads();
        __syncthreads();
    }
    __syncthreads();

    // Placement via precomputed ranks: plain LDS writes, no atomics.
#pragma unroll
    for (int i = 0; i < 2; ++i)
#pragma unroll
        for (int c = 0; c < 4; ++c)
            sorted[lstart[ix[i][c] >> BIN_SHIFT] + rr[4 * i + c]] =
                make_uint2(__float_as_uint(vv[i][c]), ix[i][c]);
    __syncthreads();

    // Flush: ~32-pair (256 B) runs -> mostly-full-line cached stores.
#pragma unroll
    for (int k = 0; k < 8; ++k) {
        int j = k * 1024 + tid;
        uint2 p = sorted[j];
        u32 b = p.y >> BIN_SHIFT;
        u32 r = (u32)j + diff[b];                  // global rank within bin
        if (r < (u32)CAP)                          // overflow drop-guard
            slab[(size_t)(bb + b) * CAP + r] = make_uint2(p.x, p.y & BIN_MASK);
    }
}

// ---------------- kB: contiguous slab read + LDS accumulate + NT stream ----------------
__global__ __launch_bounds__(1024, 2) void kB_accum(const nat_u4* __restrict__ slab4,
                                                    const u32* __restrict__ cursor,
                                                    float* __restrict__ out) {
    __shared__ float acc[BIN_FLOATS];   // 64 KB
    const int bin = blockIdx.x, tid = threadIdx.x;

    nat_f4* a4 = (nat_f4*)acc;
#pragma unroll
    for (int i = 0; i < 4; ++i) a4[tid + i * 1024] = (nat_f4)0.f;
    u32 cnt = cursor[bin];
    if (cnt > (u32)CAP) cnt = (u32)CAP;
    const nat_u4* seg4 = slab4 + (size_t)bin * (CAP / 2);
    __syncthreads();

    // Contiguous gather: 4 pairs (2 independent uint4 loads) per iteration.
    const u32 quarter = cnt >> 2;       // pairs/4
    for (u32 j = tid; j < quarter; j += 1024) {
        nat_u4 p0 = seg4[2 * j + 0];
        nat_u4 p1 = seg4[2 * j + 1];
        atomicAdd(&acc[p0.y], __uint_as_float(p0.x));
        atomicAdd(&acc[p0.w], __uint_as_float(p0.z));
        atomicAdd(&acc[p1.y], __uint_as_float(p1.x));
        atomicAdd(&acc[p1.w], __uint_as_float(p1.z));
    }
    // Tail (cnt % 4 pairs), single thread.
    if (tid == 0) {
        const uint2* seg2 = (const uint2*)seg4;
        for (u32 q = quarter << 2; q < cnt; ++q) {
            uint2 p = seg2[q];
            atomicAdd(&acc[p.y], __uint_as_float(p.x));
        }
    }
    __syncthreads();

    // Stream bin out (nontemporal: written once, never re-read).
    nat_f4* o4 = (nat_f4*)(out + ((size_t)bin << BIN_SHIFT));
#pragma unroll
    for (int i = 0; i < 4; ++i)
        __builtin_nontemporal_store(a4[tid + i * 1024], &o4[tid + i * 1024]);
}

// ---------------- Fallback (ws too small): zero + device-atomic scatter ----------------
__global__ __launch_bounds__(256) void zero_out(float4* __restrict__ out) {
    int t = blockIdx.x * blockDim.x + threadIdx.x;
    out[t] = make_float4(0.f, 0.f, 0.f, 0.f);
}
__global__ __launch_bounds__(256) void scatter_atomic(const float4* __restrict__ in,
                                                      const int4* __restrict__ idx,
                                                      float* __restrict__ out) {
    int t = blockIdx.x * blockDim.x + threadIdx.x;
    float4 v = in[t];
    int4 ix = idx[t];
    float* obase = out + ((size_t)(t >> 18) << 22);
    atomicAdd(obase + ix.x, v.x);
    atomicAdd(obase + ix.y, v.y);
    atomicAdd(obase + ix.z, v.z);
    atomicAdd(obase + ix.w, v.w);
}

extern "C" void kernel_launch(void* const* d_in, const int* in_sizes, int n_in,
                              void* d_out, int out_size, void* d_ws, size_t ws_size,
                              hipStream_t stream) {
    const float4* val4 = (const float4*)d_in[0];
    const int4*   idx4 = (const int4*)d_in[1];
    float*        out  = (float*)d_out;

    if (ws_size < WS_NEEDED) {
        // Fallback: fast zero + device atomics (R1 structure).
        zero_out<<<(out_size / 4) / 256, 256, 0, stream>>>((float4*)d_out);
        scatter_atomic<<<(N / 4) / 256, 256, 0, stream>>>(val4, idx4, out);
        return;
    }

    uint2* slab   = (uint2*)d_ws;
    u32*   cursor = (u32*)((char*)d_ws + SLAB_BYTES);

    (void)hipMemsetAsync(cursor, 0, NBINS * sizeof(u32), stream);
    kA_sort <<<KA_BLOCKS, 1024, 0, stream>>>((const nat_u4*)idx4, (const nat_f4*)val4,
                                             slab, cursor);
    kB_accum<<<NBINS, 1024, 0, stream>>>((const nat_u4*)d_ws, cursor, out);
}